// Round 1
// baseline (4934.261 us; speedup 1.0000x reference)
//
#include <hip/hip_runtime.h>

// ---------------------------------------------------------------------------
// Model: two 2-layer LSTMs (H=1024) + 29-step autoregressive scan (state
// resets each step => scan needs only Wih matmuls). All matmuls via f16 MFMA
// (16x16x32), fp32 accumulate, gates fused in GEMM epilogue.
// ---------------------------------------------------------------------------

#define B_    2048
#define OBS_  20
#define PRED_ 30
#define F_    16
#define H_    1024
#define GN_   4096   // 4*H

typedef _Float16 f16;
typedef _Float16 f16x8 __attribute__((ext_vector_type(8)));
typedef _Float16 f16x4 __attribute__((ext_vector_type(4)));
typedef float    f32x4 __attribute__((ext_vector_type(4)));

__device__ __forceinline__ float fast_sigmoid(float x) {
  return 1.0f / (1.0f + __expf(-x));
}
__device__ __forceinline__ float fast_tanh(float x) {
  float ax = fabsf(x);
  float e  = __expf(-2.0f * ax);      // in (0,1], no overflow
  float r  = (1.0f - e) / (1.0f + e);
  return copysignf(r, x);
}

// ---------------------------------------------------------------------------
// Fused LSTM step:  gates = [A16@W16^T] + [A0@W0^T] + [A1@W1^T] + bias
// then c' = sig(f)*c + sig(i)*tanh(g);  h = sig(o)*tanh(c')
// WG tile: 128 batch rows x 32 j-columns; effective GEMM N=128 (4 gate blocks
// of 32). Wave grid 2x2; each wave 64 rows x (4 gates x 16 j). Lane's 4
// N-fragments == the 4 gates of its j => epilogue is lane-local.
// LDS: [128][BK=64] f16 tiles, XOR slot-swizzle (slot ^= row&7), staged via
// global_load_lds(16B) with inverse-swizzled global source (linear LDS dest).
// ---------------------------------------------------------------------------
template<int K16, int NMAIN, int HASC, int WRITEC>
__global__ __launch_bounds__(256, 2)
void lstm_step(const f16* __restrict__ A16, const f16* __restrict__ W16,
               const f16* __restrict__ A0,  const f16* __restrict__ W0,
               const f16* __restrict__ A1,  const f16* __restrict__ W1,
               const float* __restrict__ bias,
               const float* __restrict__ cin, float* __restrict__ cout,
               f16* __restrict__ hout)
{
  __shared__ f16 lA[2][128 * 64];
  __shared__ f16 lB[2][128 * 64];

  const int tid  = threadIdx.x;
  const int lane = tid & 63;
  const int wv   = tid >> 6;
  const int wr   = wv >> 1;      // wave row 0..1
  const int wc   = wv & 1;       // wave col 0..1
  const int bm   = blockIdx.x >> 5;   // 0..15  (batch block)
  const int bn   = blockIdx.x & 31;   // 0..31  (j block)
  const int b0   = bm * 128;
  const int j0   = bn * 32;

  const int lcol = lane & 15;
  const int lkq  = lane >> 4;    // 0..3
  const int jcol = j0 + wc * 16 + lcol;

  // init acc with bias (column-constant across the 4 row-regs)
  f32x4 acc[4][4];
#pragma unroll
  for (int g = 0; g < 4; ++g) {
    float bv = bias[g * H_ + jcol];
#pragma unroll
    for (int m = 0; m < 4; ++m) acc[m][g] = (f32x4){bv, bv, bv, bv};
  }

  // ---- staging helpers (linear LDS dest, inverse-swizzled global source) ----
  auto stageA = [&](int buf, const f16* Asrc, int k0) {
#pragma unroll
    for (int cc = 0; cc < 4; ++cc) {
      int o  = cc * 4096 + tid * 16;      // byte offset in tile
      int rr = o >> 7;                    // row 0..127
      int sp = (o >> 4) & 7;              // physical 16B slot
      int sl = sp ^ (rr & 7);             // logical slot
      const f16* gp = Asrc + (b0 + rr) * H_ + k0 + sl * 8;
      __builtin_amdgcn_global_load_lds(
          (const __attribute__((address_space(1))) void*)gp,
          (__attribute__((address_space(3))) void*)((char*)&lA[buf][0] + o),
          16, 0, 0);
    }
  };
  auto stageB = [&](int buf, const f16* Wsrc, int k0) {
#pragma unroll
    for (int cc = 0; cc < 4; ++cc) {
      int o  = cc * 4096 + tid * 16;
      int rr = o >> 7;
      int sp = (o >> 4) & 7;
      int sl = sp ^ (rr & 7);
      int row = (rr >> 5) * H_ + j0 + (rr & 31);   // gate*1024 + j
      const f16* gp = Wsrc + row * H_ + k0 + sl * 8;
      __builtin_amdgcn_global_load_lds(
          (const __attribute__((address_space(1))) void*)gp,
          (__attribute__((address_space(3))) void*)((char*)&lB[buf][0] + o),
          16, 0, 0);
    }
  };

  // issue first tile's loads before the K16 work (overlap)
  if (NMAIN > 0) { stageA(0, A0, 0); stageB(0, W0, 0); }

  // ---- K=16 input term (zero-padded to one K=32 MFMA slice) ----
  if (K16) {
    f16x8 za = {0, 0, 0, 0, 0, 0, 0, 0};
    f16x8 af[4], bf[4];
#pragma unroll
    for (int m = 0; m < 4; ++m) {
      if (lkq < 2) {
        int row = b0 + wr * 64 + m * 16 + lcol;
        af[m] = *(const f16x8*)(A16 + row * 16 + lkq * 8);
      } else af[m] = za;
    }
#pragma unroll
    for (int g = 0; g < 4; ++g) {
      if (lkq < 2) {
        int row = g * H_ + j0 + wc * 16 + lcol;
        bf[g] = *(const f16x8*)(W16 + row * 16 + lkq * 8);
      } else bf[g] = za;
    }
#pragma unroll
    for (int m = 0; m < 4; ++m)
#pragma unroll
      for (int g = 0; g < 4; ++g)
        acc[m][g] = __builtin_amdgcn_mfma_f32_16x16x32_f16(af[m], bf[g], acc[m][g], 0, 0, 0);
  }

  // ---- main K loop (double-buffered) ----
  if (NMAIN > 0) {
    const int NT = NMAIN * 16;   // K tiles of 64 per operand (1024/64)
    __syncthreads();
    int cur = 0;
    for (int t = 0; t < NT; ++t) {
      if (t + 1 < NT) {
        int tn = t + 1;
        const f16* As = (NMAIN == 2 && tn >= 16) ? A1 : A0;
        const f16* Ws = (NMAIN == 2 && tn >= 16) ? W1 : W0;
        int k0 = (tn & 15) * 64;
        stageA(cur ^ 1, As, k0);
        stageB(cur ^ 1, Ws, k0);
      }
#pragma unroll
      for (int ks = 0; ks < 2; ++ks) {
        f16x8 av[4], bv_[4];
#pragma unroll
        for (int m = 0; m < 4; ++m) {
          int ar = wr * 64 + m * 16 + lcol;
          int sl = (ks * 4 + lkq) ^ (ar & 7);
          av[m] = *(const f16x8*)&lA[cur][ar * 64 + sl * 8];
        }
#pragma unroll
        for (int g = 0; g < 4; ++g) {
          int br = g * 32 + wc * 16 + lcol;
          int sl = (ks * 4 + lkq) ^ (br & 7);
          bv_[g] = *(const f16x8*)&lB[cur][br * 64 + sl * 8];
        }
#pragma unroll
        for (int m = 0; m < 4; ++m)
#pragma unroll
          for (int g = 0; g < 4; ++g)
            acc[m][g] = __builtin_amdgcn_mfma_f32_16x16x32_f16(av[m], bv_[g], acc[m][g], 0, 0, 0);
      }
      __syncthreads();
      cur ^= 1;
    }
  }

  // ---- fused gate epilogue ----
#pragma unroll
  for (int m = 0; m < 4; ++m) {
    int brow0 = b0 + wr * 64 + m * 16 + lkq * 4;
#pragma unroll
    for (int r = 0; r < 4; ++r) {
      int bi = (brow0 + r) * H_ + jcol;
      float gi = acc[m][0][r];
      float gf = acc[m][1][r];
      float gg = acc[m][2][r];
      float go = acc[m][3][r];
      float cold = HASC ? cin[bi] : 0.0f;
      float cn = fast_sigmoid(gf) * cold + fast_sigmoid(gi) * fast_tanh(gg);
      float hv = fast_sigmoid(go) * fast_tanh(cn);
      if (WRITEC) cout[bi] = cn;
      hout[bi] = (f16)hv;
    }
  }
}

// ---------------------------------------------------------------------------
// projection + scan update:
//   t = tanh(h1 @ Wl^T + bl)
//   MODE 0:  v = sv * t                   (v-LSTM head)
//   MODE 1:  a = t; v += sv*a; x += v; out_t = x; a16 = (f16)a
// ---------------------------------------------------------------------------
template<int MODE>
__global__ __launch_bounds__(256)
void proj_update(const f16* __restrict__ h1, const float* __restrict__ Wl,
                 const float* __restrict__ bl, const float* __restrict__ sv,
                 float* __restrict__ v_buf, float* __restrict__ x_buf,
                 float* __restrict__ out_t, f16* __restrict__ a16)
{
  __shared__ f16 lh[16 * 1024];
  const int b0r = blockIdx.x * 16;
  const int tid = threadIdx.x;
#pragma unroll
  for (int c = 0; c < 8; ++c) {
    int o = c * 256 + tid;                   // 8-f16 granule index
    *(f16x8*)&lh[o * 8] = *(const f16x8*)&h1[b0r * 1024 + o * 8];
  }
  __syncthreads();
  const int br = tid >> 4;
  const int f  = tid & 15;
  float s0 = 0, s1 = 0, s2 = 0, s3 = 0;
  const float4* wp = (const float4*)(Wl + f * 1024);
#pragma unroll 4
  for (int k8 = 0; k8 < 128; ++k8) {
    f16x8 hv = *(const f16x8*)&lh[br * 1024 + k8 * 8];
    float4 w0 = wp[k8 * 2], w1 = wp[k8 * 2 + 1];
    s0 += (float)hv[0] * w0.x + (float)hv[4] * w1.x;
    s1 += (float)hv[1] * w0.y + (float)hv[5] * w1.y;
    s2 += (float)hv[2] * w0.z + (float)hv[6] * w1.z;
    s3 += (float)hv[3] * w0.w + (float)hv[7] * w1.w;
  }
  float t = fast_tanh(bl[f] + ((s0 + s1) + (s2 + s3)));
  int idx = (b0r + br) * F_ + f;
  if (MODE == 0) {
    v_buf[idx] = sv[0] * t;
  } else {
    float v = v_buf[idx] + sv[0] * t;
    v_buf[idx] = v;
    float x = x_buf[idx] + v;
    x_buf[idx] = x;
    out_t[idx] = x;
    a16[idx] = (f16)t;
  }
}

// ---------------------------------------------------------------------------
// input prep: x0, yT (second output), v_seq (f16), a_seq (f16)
// ---------------------------------------------------------------------------
__global__ void prep_kernel(const float* __restrict__ x_in, const float* __restrict__ y,
                            const float* __restrict__ v_in, const float* __restrict__ sx,
                            float* __restrict__ out, float* __restrict__ x_buf,
                            f16* __restrict__ xt16, f16* __restrict__ at16)
{
  const float s = sx[0];
  int gid = blockIdx.x * blockDim.x + threadIdx.x;
  int gs  = gridDim.x * blockDim.x;
  for (int i = gid; i < B_ * OBS_ * F_; i += gs) {
    int b = i / (OBS_ * F_);
    int rem = i - b * (OBS_ * F_);
    int t = rem >> 4;
    int f = rem & 15;
    float v = v_in[i];
    xt16[(t * B_ + b) * F_ + f] = (f16)v;
    if (t < OBS_ - 1) {
      float v2 = v_in[i + F_];
      at16[(t * B_ + b) * F_ + f] = (f16)(v2 - v);
    }
  }
  for (int i = gid; i < PRED_ * B_ * F_; i += gs) {
    int t = i / (B_ * F_);
    int rem = i - t * (B_ * F_);
    int b = rem >> 4;
    int f = rem & 15;
    out[PRED_ * B_ * F_ + i] = s * y[(b * PRED_ + t) * F_ + f];
  }
  for (int i = gid; i < B_ * F_; i += gs) {
    int b = i >> 4;
    int f = i & 15;
    x_buf[i] = s * x_in[(b * OBS_ + (OBS_ - 1)) * F_ + f];
  }
}

// ---------------------------------------------------------------------------
// weight conversion fp32 -> f16 + bias sums (bih + bhh)
// ---------------------------------------------------------------------------
struct ConvArgs {
  const float* src[8];
  f16*         dst[8];
  int          n[8];
  const float* b1[4];
  const float* b2[4];
  float*       bd[4];
};

__global__ void convw(ConvArgs a)
{
  int gid = blockIdx.x * blockDim.x + threadIdx.x;
  int gs  = gridDim.x * blockDim.x;
#pragma unroll
  for (int s = 0; s < 8; ++s) {
    int n4 = a.n[s] >> 2;
    for (int i = gid; i < n4; i += gs) {
      float4 v = ((const float4*)a.src[s])[i];
      f16x4 d = {(f16)v.x, (f16)v.y, (f16)v.z, (f16)v.w};
      ((f16x4*)a.dst[s])[i] = d;
    }
  }
#pragma unroll
  for (int s = 0; s < 4; ++s) {
    for (int i = gid; i < GN_; i += gs) a.bd[s][i] = a.b1[s][i] + a.b2[s][i];
  }
}

// ---------------------------------------------------------------------------
extern "C" void kernel_launch(void* const* d_in, const int* in_sizes, int n_in,
                              void* d_out, int out_size, void* d_ws, size_t ws_size,
                              hipStream_t stream)
{
  (void)in_sizes; (void)n_in; (void)out_size; (void)ws_size;

  const float* x_in  = (const float*)d_in[0];
  const float* y     = (const float*)d_in[1];
  const float* v_in  = (const float*)d_in[2];
  const float* sx    = (const float*)d_in[3];
  const float* sv    = (const float*)d_in[4];
  const float* vWih0 = (const float*)d_in[5];
  const float* vWhh0 = (const float*)d_in[6];
  const float* vbih0 = (const float*)d_in[7];
  const float* vbhh0 = (const float*)d_in[8];
  const float* vWih1 = (const float*)d_in[9];
  const float* vWhh1 = (const float*)d_in[10];
  const float* vbih1 = (const float*)d_in[11];
  const float* vbhh1 = (const float*)d_in[12];
  const float* vWl   = (const float*)d_in[13];
  const float* vbl   = (const float*)d_in[14];
  const float* aWih0 = (const float*)d_in[15];
  const float* aWhh0 = (const float*)d_in[16];
  const float* abih0 = (const float*)d_in[17];
  const float* abhh0 = (const float*)d_in[18];
  const float* aWih1 = (const float*)d_in[19];
  const float* aWhh1 = (const float*)d_in[20];
  const float* abih1 = (const float*)d_in[21];
  const float* abhh1 = (const float*)d_in[22];
  const float* aWl   = (const float*)d_in[23];
  const float* abl   = (const float*)d_in[24];
  float* out = (float*)d_out;

  char* ws = (char*)d_ws;
  size_t off = 0;
  auto alloc = [&](size_t bytes) {
    char* p = ws + off;
    off += (bytes + 255) & ~(size_t)255;
    return p;
  };
  f16* vWih0f = (f16*)alloc((size_t)GN_ * F_ * 2);
  f16* vWhh0f = (f16*)alloc((size_t)GN_ * H_ * 2);
  f16* vWih1f = (f16*)alloc((size_t)GN_ * H_ * 2);
  f16* vWhh1f = (f16*)alloc((size_t)GN_ * H_ * 2);
  f16* aWih0f = (f16*)alloc((size_t)GN_ * F_ * 2);
  f16* aWhh0f = (f16*)alloc((size_t)GN_ * H_ * 2);
  f16* aWih1f = (f16*)alloc((size_t)GN_ * H_ * 2);
  f16* aWhh1f = (f16*)alloc((size_t)GN_ * H_ * 2);
  float* vb0 = (float*)alloc(GN_ * 4);
  float* vb1 = (float*)alloc(GN_ * 4);
  float* ab0 = (float*)alloc(GN_ * 4);
  float* ab1 = (float*)alloc(GN_ * 4);
  f16* xt16 = (f16*)alloc((size_t)OBS_ * B_ * F_ * 2);
  f16* at16 = (f16*)alloc((size_t)(OBS_ - 1) * B_ * F_ * 2);
  f16* h0a = (f16*)alloc((size_t)B_ * H_ * 2);
  f16* h0b = (f16*)alloc((size_t)B_ * H_ * 2);
  f16* h1a = (f16*)alloc((size_t)B_ * H_ * 2);
  f16* h1b = (f16*)alloc((size_t)B_ * H_ * 2);
  float* c0 = (float*)alloc((size_t)B_ * H_ * 4);
  float* c1 = (float*)alloc((size_t)B_ * H_ * 4);
  f16* a16   = (f16*)alloc((size_t)B_ * F_ * 2);
  float* v_buf = (float*)alloc((size_t)B_ * F_ * 4);
  float* x_buf = (float*)alloc((size_t)B_ * F_ * 4);

  // weight conversion + bias sums
  ConvArgs ca;
  ca.src[0] = vWih0; ca.dst[0] = vWih0f; ca.n[0] = GN_ * F_;
  ca.src[1] = vWhh0; ca.dst[1] = vWhh0f; ca.n[1] = GN_ * H_;
  ca.src[2] = vWih1; ca.dst[2] = vWih1f; ca.n[2] = GN_ * H_;
  ca.src[3] = vWhh1; ca.dst[3] = vWhh1f; ca.n[3] = GN_ * H_;
  ca.src[4] = aWih0; ca.dst[4] = aWih0f; ca.n[4] = GN_ * F_;
  ca.src[5] = aWhh0; ca.dst[5] = aWhh0f; ca.n[5] = GN_ * H_;
  ca.src[6] = aWih1; ca.dst[6] = aWih1f; ca.n[6] = GN_ * H_;
  ca.src[7] = aWhh1; ca.dst[7] = aWhh1f; ca.n[7] = GN_ * H_;
  ca.b1[0] = vbih0; ca.b2[0] = vbhh0; ca.bd[0] = vb0;
  ca.b1[1] = vbih1; ca.b2[1] = vbhh1; ca.bd[1] = vb1;
  ca.b1[2] = abih0; ca.b2[2] = abhh0; ca.bd[2] = ab0;
  ca.b1[3] = abih1; ca.b2[3] = abhh1; ca.bd[3] = ab1;
  convw<<<1024, 256, 0, stream>>>(ca);
  prep_kernel<<<1024, 256, 0, stream>>>(x_in, y, v_in, sx, out, x_buf, xt16, at16);

  dim3 gG(512), gB(256);

  // ---- v-LSTM over v_seq (T=20) ----
  const f16 *h0p = nullptr, *h1p = nullptr;
  for (int t = 0; t < OBS_; ++t) {
    f16* h0o = (t & 1) ? h0b : h0a;
    f16* h1o = (t & 1) ? h1b : h1a;
    if (t == 0) {
      lstm_step<1, 0, 0, 1><<<gG, gB, 0, stream>>>(xt16 + (size_t)t * B_ * F_, vWih0f,
          nullptr, nullptr, nullptr, nullptr, vb0, nullptr, c0, h0o);
      lstm_step<0, 1, 0, 1><<<gG, gB, 0, stream>>>(nullptr, nullptr, h0o, vWih1f,
          nullptr, nullptr, vb1, nullptr, c1, h1o);
    } else {
      lstm_step<1, 1, 1, 1><<<gG, gB, 0, stream>>>(xt16 + (size_t)t * B_ * F_, vWih0f,
          h0p, vWhh0f, nullptr, nullptr, vb0, c0, c0, h0o);
      lstm_step<0, 2, 1, 1><<<gG, gB, 0, stream>>>(nullptr, nullptr, h0o, vWih1f,
          h1p, vWhh1f, vb1, c1, c1, h1o);
    }
    h0p = h0o; h1p = h1o;
  }
  proj_update<0><<<128, 256, 0, stream>>>(h1p, vWl, vbl, sv, v_buf, nullptr, nullptr, nullptr);

  // ---- a-LSTM over a_seq (T=19) ----
  h0p = nullptr; h1p = nullptr;
  for (int t = 0; t < OBS_ - 1; ++t) {
    f16* h0o = (t & 1) ? h0b : h0a;
    f16* h1o = (t & 1) ? h1b : h1a;
    if (t == 0) {
      lstm_step<1, 0, 0, 1><<<gG, gB, 0, stream>>>(at16 + (size_t)t * B_ * F_, aWih0f,
          nullptr, nullptr, nullptr, nullptr, ab0, nullptr, c0, h0o);
      lstm_step<0, 1, 0, 1><<<gG, gB, 0, stream>>>(nullptr, nullptr, h0o, aWih1f,
          nullptr, nullptr, ab1, nullptr, c1, h1o);
    } else {
      lstm_step<1, 1, 1, 1><<<gG, gB, 0, stream>>>(at16 + (size_t)t * B_ * F_, aWih0f,
          h0p, aWhh0f, nullptr, nullptr, ab0, c0, c0, h0o);
      lstm_step<0, 2, 1, 1><<<gG, gB, 0, stream>>>(nullptr, nullptr, h0o, aWih1f,
          h1p, aWhh1f, ab1, c1, c1, h1o);
    }
    h0p = h0o; h1p = h1o;
  }
  // a-head + initial update => out[0]
  proj_update<1><<<128, 256, 0, stream>>>(h1p, aWl, abl, sv, v_buf, x_buf, out, a16);

  // ---- autoregressive scan (29 steps, zero-state => Wih-only) ----
  for (int t = 1; t < PRED_; ++t) {
    lstm_step<1, 0, 0, 0><<<gG, gB, 0, stream>>>(a16, aWih0f,
        nullptr, nullptr, nullptr, nullptr, ab0, nullptr, nullptr, h0a);
    lstm_step<0, 1, 0, 0><<<gG, gB, 0, stream>>>(nullptr, nullptr, h0a, aWih1f,
        nullptr, nullptr, ab1, nullptr, nullptr, h1a);
    proj_update<1><<<128, 256, 0, stream>>>(h1a, aWl, abl, sv, v_buf, x_buf,
        out + (size_t)t * B_ * F_, a16);
  }
}